// Round 3
// baseline (681.397 us; speedup 1.0000x reference)
//
#include <hip/hip_runtime.h>

// Problem constants (from reference)
#define E_TOT   50000
#define DD      256
#define KSEQ    8
#define NHEAD   4
#define HDIM    64
#define TE      4        // edges per group
#define NGROUP  (E_TOT / TE)   // 12500
#define SCALE_V 0.125f   // HD^-0.5
#define PGRID   512      // persistent grid: 2 WGs/CU

typedef __attribute__((ext_vector_type(4))) float f32x4;
typedef __attribute__((ext_vector_type(8))) short short8;

__device__ __forceinline__ unsigned short f2bf(float f) {
    unsigned u = __float_as_uint(f);
    u += 0x7fffu + ((u >> 16) & 1u);   // RNE
    return (unsigned short)(u >> 16);
}
__device__ __forceinline__ float bf2f(unsigned short h) {
    return __uint_as_float(((unsigned)h) << 16);
}
__device__ __forceinline__ float gelu_exact(float x) {
    return 0.5f * x * (1.0f + erff(x * 0.70710678118654752440f));
}
__device__ __forceinline__ float sigmoidf(float x) {
    return 1.0f / (1.0f + __expf(-x));
}

// ---------------------------------------------------------------------------
// Kernel P: convert Wq/Wk (f32 [k][n]) -> bf16 transposed [n][k]; also
// convert We1 (f32 [256][128]) -> bf16 same layout.
// ---------------------------------------------------------------------------
__global__ void prep_weights(const float* __restrict__ Wq,
                             const float* __restrict__ Wk,
                             const float* __restrict__ We1,
                             unsigned short* __restrict__ wqT,
                             unsigned short* __restrict__ wkT,
                             unsigned short* __restrict__ wb1) {
    int i = blockIdx.x * 256 + threadIdx.x;      // grid 640*256 = 163840
    if (i < 131072) {
        int which = i >> 16;
        int j = i & 65535;                        // flat [k][n]
        int k = j >> 8, n = j & 255;
        const float* W = which ? Wk : Wq;
        unsigned short* o = which ? wkT : wqT;
        o[n * 256 + k] = f2bf(W[j]);
    } else {
        int j = i - 131072;                       // 0..32767
        wb1[j] = f2bf(We1[j]);
    }
}

// ---------------------------------------------------------------------------
// Kernel A: per-edge cosine similarity + edge-plausibility MLP.
// One wave (64 lanes) per edge; 4 edges per 256-thread block.
// ---------------------------------------------------------------------------
__global__ void score_attr_edge(const float* __restrict__ x_i,
                                const float* __restrict__ x_j,
                                const float* __restrict__ emb,
                                const unsigned short* __restrict__ wb1,
                                const float* __restrict__ be1,
                                const float* __restrict__ We2,
                                const float* __restrict__ be2,
                                float* __restrict__ attr_out,
                                float* __restrict__ edge_out) {
    __shared__ float sEmb[4][DD];
    const int wv = threadIdx.x >> 6;
    const int l  = threadIdx.x & 63;
    const int e  = blockIdx.x * 4 + wv;

    // ---- (A) cosine similarity ----
    f32x4 a = *(const f32x4*)(x_i + (size_t)e * DD + l * 4);
    f32x4 b = *(const f32x4*)(x_j + (size_t)e * DD + l * 4);
    f32x4 ev = *(const f32x4*)(emb + (size_t)e * DD + l * 4);
    float dot = a[0]*b[0] + a[1]*b[1] + a[2]*b[2] + a[3]*b[3];
    float ni  = a[0]*a[0] + a[1]*a[1] + a[2]*a[2] + a[3]*a[3];
    float nj  = b[0]*b[0] + b[1]*b[1] + b[2]*b[2] + b[3]*b[3];
    #pragma unroll
    for (int off = 1; off < 64; off <<= 1) {
        dot += __shfl_xor(dot, off);
        ni  += __shfl_xor(ni,  off);
        nj  += __shfl_xor(nj,  off);
    }
    float na = fmaxf(sqrtf(ni), 1e-8f);
    float nb = fmaxf(sqrtf(nj), 1e-8f);
    if (l == 0) attr_out[e] = (dot / (na * nb) + 1.0f) * 0.5f;

    // ---- (C) edge MLP: 256 -> 128 (gelu) -> 1 (sigmoid); lane l owns
    // hidden cols 2l, 2l+1 (one u32 bf16-pair load per k) ----
    sEmb[wv][l*4+0] = ev[0]; sEmb[wv][l*4+1] = ev[1];
    sEmb[wv][l*4+2] = ev[2]; sEmb[wv][l*4+3] = ev[3];
    __syncthreads();

    float acc0 = 0.f, acc1 = 0.f;
    #pragma unroll 8
    for (int k = 0; k < DD; ++k) {
        float ek = sEmb[wv][k];
        unsigned u = *(const unsigned*)(wb1 + k * 128 + 2 * l);
        acc0 = fmaf(ek, bf2f((unsigned short)(u & 0xffffu)), acc0);
        acc1 = fmaf(ek, bf2f((unsigned short)(u >> 16)),     acc1);
    }
    float h0 = gelu_exact(acc0 + be1[2 * l]);
    float h1 = gelu_exact(acc1 + be1[2 * l + 1]);
    float s  = h0 * We2[2 * l] + h1 * We2[2 * l + 1];
    #pragma unroll
    for (int off = 1; off < 64; off <<= 1) s += __shfl_xor(s, off);
    if (l == 0) edge_out[e] = sigmoidf(s + be2[0]);
}

// ---------------------------------------------------------------------------
// Kernel B: persistent fused attention activity score + final combine MLP.
// 512 resident WGs, each loops over ~24 groups of TE=4 edges with
// cross-iteration register prefetch (stg[16] f32x4 = next group's h_i|h_j).
// ---------------------------------------------------------------------------
__device__ __forceinline__ void issue_loads(f32x4 stg[16],
                                            const float* __restrict__ h_i,
                                            const float* __restrict__ h_j,
                                            int g, int t) {
    const size_t base = (size_t)g * (TE * KSEQ * DD);
    #pragma unroll
    for (int i = 0; i < 16; ++i) {
        const int f = i * 256 + t;                 // float4 index 0..4095
        const float* src = (f >> 11) ? h_j : h_i;  // compile-time per i
        stg[i] = *(const f32x4*)(src + base + (size_t)(f & 2047) * 4);
    }
}

__device__ __forceinline__ void do_gemm(const unsigned short (*A)[DD + 8],
                                        const unsigned short* __restrict__ Wt,
                                        f32x4 acc[2][4], int l, int w) {
    const int lr = l & 15, lq = l >> 4;
    #pragma unroll
    for (int ks = 0; ks < 8; ++ks) {
        const short8 a0 = *(const short8*)&A[lr][ks * 32 + lq * 8];
        const short8 a1 = *(const short8*)&A[16 + lr][ks * 32 + lq * 8];
        #pragma unroll
        for (int n = 0; n < 4; ++n) {
            const int col = (w * 4 + n) * 16 + lr;
            const short8 bv = *(const short8*)(Wt + col * 256 + ks * 32 + lq * 8);
            acc[0][n] = __builtin_amdgcn_mfma_f32_16x16x32_bf16(a0, bv, acc[0][n], 0, 0, 0);
            acc[1][n] = __builtin_amdgcn_mfma_f32_16x16x32_bf16(a1, bv, acc[1][n], 0, 0, 0);
        }
    }
}

__device__ __forceinline__ void writeback(unsigned short (*A)[DD + 8],
                                          const f32x4 acc[2][4],
                                          const float* __restrict__ bias,
                                          int l, int w) {
    const int lr = l & 15, lq = l >> 4;
    #pragma unroll
    for (int n = 0; n < 4; ++n) {
        const int col = (w * 4 + n) * 16 + lr;
        const float bs = bias[col];
        #pragma unroll
        for (int m = 0; m < 2; ++m) {
            #pragma unroll
            for (int v = 0; v < 4; ++v) {
                const int row = m * 16 + lq * 4 + v;  // verified C/D layout
                A[row][col] = f2bf(acc[m][n][v] + bs);
            }
        }
    }
}

__global__ __launch_bounds__(256, 2)
void fused_attn(const float* __restrict__ h_i,
                const float* __restrict__ h_j,
                const unsigned short* __restrict__ wqT,
                const unsigned short* __restrict__ wkT,
                const float* __restrict__ bq,
                const float* __restrict__ bk,
                const float* __restrict__ Wo1,
                const float* __restrict__ bo1,
                const float* __restrict__ Wo2,
                const float* __restrict__ bo2,
                const float* __restrict__ attr_ws,
                const float* __restrict__ edge_ws,
                float* __restrict__ out) {
    // Abf[0]=h_i tile then Q (bf16), Abf[1]=h_j tile then K. +8 pad kills the
    // 512B-stride bank conflict on 16-lane fragment reads.
    __shared__ unsigned short Abf[2][TE * KSEQ][DD + 8];
    __shared__ float actLds[TE];

    const int t = threadIdx.x;
    const int w = t >> 6;          // wave 0..3
    const int l = t & 63;
    const int nwg = gridDim.x;

    f32x4 stg[16];
    int g = blockIdx.x;
    if (g < NGROUP) issue_loads(stg, h_i, h_j, g, t);   // prologue prefetch

    for (; g < NGROUP; g += nwg) {
        __syncthreads();   // prev iter done reading Abf / actLds

        // ---- convert prefetched registers -> bf16 LDS tiles ----
        #pragma unroll
        for (int i = 0; i < 16; ++i) {
            const int f  = i * 256 + t;
            const int T  = f >> 11;
            const int ff = f & 2047;
            ushort4 u = make_ushort4(f2bf(stg[i][0]), f2bf(stg[i][1]),
                                     f2bf(stg[i][2]), f2bf(stg[i][3]));
            *(ushort4*)&Abf[T][ff >> 6][(ff & 63) * 4] = u;
        }
        __syncthreads();

        // ---- burst-issue next group's 16 loads; pin them here ----
        if (g + nwg < NGROUP) issue_loads(stg, h_i, h_j, g + nwg, t);
        __builtin_amdgcn_sched_barrier(0);

        // ---- GEMMs: Q = h_i@Wq, K = h_j@Wk (pure reads, no barrier) ----
        f32x4 accQ[2][4] = {};
        f32x4 accK[2][4] = {};
        do_gemm(Abf[0], wqT, accQ, l, w);
        do_gemm(Abf[1], wkT, accK, l, w);
        __syncthreads();                 // all waves done reading Abf
        writeback(Abf[0], accQ, bq, l, w);
        writeback(Abf[1], accK, bk, l, w);
        __syncthreads();

        // ---- phase 3: scores, softmax diagonal, activity mean ----
        if (t < 128) {
            const int e = t >> 5, h = (t >> 3) & 3, q = t & 7;
            float qv[64];
            #pragma unroll
            for (int c = 0; c < 8; ++c) {
                short8 v = *(const short8*)&Abf[0][e * 8 + q][h * 64 + c * 8];
                #pragma unroll
                for (int j = 0; j < 8; ++j) qv[c * 8 + j] = bf2f((unsigned short)v[j]);
            }
            float sc[8];
            #pragma unroll
            for (int k = 0; k < 8; ++k) {
                float d = 0.f;
                #pragma unroll
                for (int c = 0; c < 8; ++c) {
                    short8 kv = *(const short8*)&Abf[1][e * 8 + k][h * 64 + c * 8];
                    #pragma unroll
                    for (int j = 0; j < 8; ++j)
                        d = fmaf(qv[c * 8 + j], bf2f((unsigned short)kv[j]), d);
                }
                sc[k] = d * SCALE_V;
            }
            float mx = sc[0];
            #pragma unroll
            for (int k = 1; k < 8; ++k) mx = fmaxf(mx, sc[k]);
            float sum = 0.f, pd = 0.f;
            #pragma unroll
            for (int k = 0; k < 8; ++k) {
                float p = __expf(sc[k] - mx);
                sum += p;
                if (k == q) pd = p;
            }
            float dg = pd / sum;                 // softmax diagonal element
            #pragma unroll
            for (int off = 1; off < 32; off <<= 1) dg += __shfl_xor(dg, off);
            if ((t & 31) == 0) actLds[e] = dg * (1.0f / 32.0f);   // mean NH*K
        }
        __syncthreads();

        // ---- phase 4: final 3 -> 16 -> 1 MLP ----
        if (t < TE) {
            const int ge = g * TE + t;
            const float s0 = attr_ws[ge];
            const float s1 = actLds[t];
            const float s2 = edge_ws[ge];
            float acc = bo2[0];
            #pragma unroll
            for (int j = 0; j < 16; ++j) {
                float z = s0 * Wo1[j] + s1 * Wo1[16 + j] + s2 * Wo1[32 + j] + bo1[j];
                acc += gelu_exact(z) * Wo2[j];
            }
            out[ge] = sigmoidf(acc);
        }
    }
}

// ---------------------------------------------------------------------------
extern "C" void kernel_launch(void* const* d_in, const int* in_sizes, int n_in,
                              void* d_out, int out_size, void* d_ws, size_t ws_size,
                              hipStream_t stream) {
    const float* x_i  = (const float*)d_in[0];
    const float* x_j  = (const float*)d_in[1];
    const float* h_i  = (const float*)d_in[2];
    const float* h_j  = (const float*)d_in[3];
    const float* emb  = (const float*)d_in[4];
    const float* Wq   = (const float*)d_in[5];
    const float* bq   = (const float*)d_in[6];
    const float* Wk   = (const float*)d_in[7];
    const float* bk   = (const float*)d_in[8];
    const float* We1  = (const float*)d_in[9];
    const float* be1  = (const float*)d_in[10];
    const float* We2  = (const float*)d_in[11];
    const float* be2  = (const float*)d_in[12];
    const float* Wo1  = (const float*)d_in[13];
    const float* bo1  = (const float*)d_in[14];
    const float* Wo2  = (const float*)d_in[15];
    const float* bo2  = (const float*)d_in[16];
    float* out = (float*)d_out;

    // workspace layout
    unsigned short* wqT = (unsigned short*)d_ws;              // 131072 B
    unsigned short* wkT = wqT + 65536;                        // 131072 B
    unsigned short* wb1 = wkT + 65536;                        //  65536 B
    float* attr_ws = (float*)((char*)d_ws + 327680);          // 200000 B
    float* edge_ws = attr_ws + E_TOT;                         // 200000 B

    prep_weights<<<640, 256, 0, stream>>>(Wq, Wk, We1, wqT, wkT, wb1);
    score_attr_edge<<<E_TOT / 4, 256, 0, stream>>>(x_i, x_j, emb, wb1, be1, We2, be2,
                                                   attr_ws, edge_ws);
    fused_attn<<<PGRID, 256, 0, stream>>>(h_i, h_j, wqT, wkT, bq, bk,
                                          Wo1, bo1, Wo2, bo2,
                                          attr_ws, edge_ws, out);
}

// Round 4
// 636.123 us; speedup vs baseline: 1.0712x; 1.0712x over previous
//
#include <hip/hip_runtime.h>

// Problem constants (from reference)
#define E_TOT   50000
#define DD      256
#define TE      4               // edges per workgroup
#define NGROUP  (E_TOT / TE)    // 12500
#define SCALE_V 0.125f          // HD^-0.5

typedef __attribute__((ext_vector_type(4))) float f32x4;
typedef __attribute__((ext_vector_type(8))) short short8;

__device__ __forceinline__ unsigned short f2bf(float f) {
    unsigned u = __float_as_uint(f);
    u += 0x7fffu + ((u >> 16) & 1u);   // RNE
    return (unsigned short)(u >> 16);
}
__device__ __forceinline__ float gelu_exact(float x) {
    return 0.5f * x * (1.0f + erff(x * 0.70710678118654752440f));
}
__device__ __forceinline__ float sigmoidf(float x) {
    return 1.0f / (1.0f + __expf(-x));
}

// Async HBM->LDS: one wave stages one 1KB row (64 lanes x 16B). Zero VGPRs.
__device__ __forceinline__ void dma_row16(const float* gbase, float* lds) {
    const int lane = threadIdx.x & 63;
    auto gp = (const __attribute__((address_space(1))) char*)(gbase) + lane * 16;
    auto lp = (__attribute__((address_space(3))) char*)(lds);
    __builtin_amdgcn_global_load_lds(gp, lp, 16, 0, 0);
}

// ---------------------------------------------------------------------------
// Kernel P: Wq/Wk (f32 [k][n]) -> bf16 [n][k]; We1 (f32 [256][128]) -> bf16
// [n][k]. B-fragments become contiguous 16B loads.
// ---------------------------------------------------------------------------
__global__ void prep_weights(const float* __restrict__ Wq,
                             const float* __restrict__ Wk,
                             const float* __restrict__ We1,
                             unsigned short* __restrict__ wqT,
                             unsigned short* __restrict__ wkT,
                             unsigned short* __restrict__ w1T) {
    int i = blockIdx.x * 256 + threadIdx.x;       // grid 640*256 = 163840
    if (i < 65536) {
        int k = i >> 8, n = i & 255;
        wqT[n * 256 + k] = f2bf(Wq[i]);
    } else if (i < 131072) {
        int j = i - 65536;
        int k = j >> 8, n = j & 255;
        wkT[n * 256 + k] = f2bf(Wk[j]);
    } else {
        int j = i - 131072;                        // 0..32767, [k][n] n<128
        int k = j >> 7, n = j & 127;
        w1T[n * 256 + k] = f2bf(We1[j]);
    }
}

// ---------------------------------------------------------------------------
// Fused kernel: everything per group of TE=4 edges.
// ---------------------------------------------------------------------------
__device__ __forceinline__ void proj_gemm(const unsigned short (*A)[260],
                                          const unsigned short* __restrict__ Wt,
                                          f32x4 acc[2][4], int lr, int lq, int w) {
    #pragma unroll
    for (int ks = 0; ks < 8; ++ks) {
        short8 a0 = *(const short8*)&A[lr][ks * 32 + lq * 8];
        short8 a1 = *(const short8*)&A[16 + lr][ks * 32 + lq * 8];
        #pragma unroll
        for (int n = 0; n < 4; ++n) {
            const int col = (w * 4 + n) * 16 + lr;
            short8 bv = *(const short8*)(Wt + col * 256 + ks * 32 + lq * 8);
            acc[0][n] = __builtin_amdgcn_mfma_f32_16x16x32_bf16(a0, bv, acc[0][n], 0, 0, 0);
            acc[1][n] = __builtin_amdgcn_mfma_f32_16x16x32_bf16(a1, bv, acc[1][n], 0, 0, 0);
        }
    }
}

__device__ __forceinline__ void writeback(unsigned short (*T)[260],
                                          const f32x4 acc[2][4],
                                          const float* __restrict__ bias,
                                          int lr, int lq, int w) {
    #pragma unroll
    for (int n = 0; n < 4; ++n) {
        const int col = (w * 4 + n) * 16 + lr;
        const float bs = bias[col];
        #pragma unroll
        for (int m = 0; m < 2; ++m) {
            #pragma unroll
            for (int v = 0; v < 4; ++v) {
                const int row = m * 16 + lq * 4 + v;   // verified C/D layout
                T[row][col] = f2bf(acc[m][n][v] + bs);
            }
        }
    }
}

__global__ __launch_bounds__(256, 3)
void fused_all(const float* __restrict__ x_i,
               const float* __restrict__ x_j,
               const float* __restrict__ h_i,
               const float* __restrict__ h_j,
               const float* __restrict__ emb,
               const unsigned short* __restrict__ wqT,
               const unsigned short* __restrict__ wkT,
               const unsigned short* __restrict__ w1T,
               const float* __restrict__ bq,
               const float* __restrict__ bk,
               const float* __restrict__ be1,
               const float* __restrict__ We2,
               const float* __restrict__ be2,
               const float* __restrict__ Wo1,
               const float* __restrict__ bo1,
               const float* __restrict__ Wo2,
               const float* __restrict__ bo2,
               float* __restrict__ out) {
    // ldsA: f32 staging (32KB used), later reused as tQ|tK bf16 tiles.
    // ldsH: bf16 [32][260] h-tile (pad 4 shorts -> 2-bank row shift, conflict-free frags)
    __shared__ __align__(16) unsigned char ldsA[33280];
    __shared__ __align__(16) unsigned char ldsH[16640];
    __shared__ float sEdgeP[4][4];     // [wave][edge] partials of edge MLP

    float* bufA32 = (float*)ldsA;
    unsigned short (*bufHI)[260] = (unsigned short (*)[260])ldsH;
    unsigned short (*tQ)[260]    = (unsigned short (*)[260])ldsA;
    unsigned short (*tK)[260]    = (unsigned short (*)[260])(ldsA + 16640);

    const int t  = threadIdx.x;
    const int w  = t >> 6;            // wave 0..3
    const int l  = t & 63;
    const int lr = l & 15, lq = l >> 4;
    const int g  = blockIdx.x;
    const size_t rowbase = (size_t)g * 32;     // global h row (32 rows per WG)

    // ---- R1: DMA h_i -> bufA32 (wave w: rows w*8..w*8+7); cosine in regs ----
    #pragma unroll
    for (int rr = 0; rr < 8; ++rr) {
        const int r = w * 8 + rr;
        dma_row16(h_i + (rowbase + r) * DD, bufA32 + r * DD);
    }
    const int e = g * TE + w;          // wave w owns edge w
    float attr;
    {
        f32x4 a = *(const f32x4*)(x_i + (size_t)e * DD + l * 4);
        f32x4 b = *(const f32x4*)(x_j + (size_t)e * DD + l * 4);
        float dot = a[0]*b[0] + a[1]*b[1] + a[2]*b[2] + a[3]*b[3];
        float ni  = a[0]*a[0] + a[1]*a[1] + a[2]*a[2] + a[3]*a[3];
        float nj  = b[0]*b[0] + b[1]*b[1] + b[2]*b[2] + b[3]*b[3];
        #pragma unroll
        for (int off = 1; off < 64; off <<= 1) {
            dot += __shfl_xor(dot, off);
            ni  += __shfl_xor(ni,  off);
            nj  += __shfl_xor(nj,  off);
        }
        attr = (dot / (fmaxf(sqrtf(ni), 1e-8f) * fmaxf(sqrtf(nj), 1e-8f)) + 1.0f) * 0.5f;
    }
    __syncthreads();                                   // B1: h_i landed

    // ---- R2: h_i f32 -> regs (stride-1, conflict-free) ----
    f32x4 stg[8];
    #pragma unroll
    for (int i = 0; i < 8; ++i) stg[i] = *(const f32x4*)(bufA32 + (i * 256 + t) * 4);
    __syncthreads();                                   // B2: bufA free

    // ---- R3: DMA h_j -> bufA32 ; write h_i bf16 -> bufHI ----
    #pragma unroll
    for (int rr = 0; rr < 8; ++rr) {
        const int r = w * 8 + rr;
        dma_row16(h_j + (rowbase + r) * DD, bufA32 + r * DD);
    }
    #pragma unroll
    for (int i = 0; i < 8; ++i) {
        const int f = i * 256 + t, r = f >> 6, u = f & 63;
        *(ushort4*)&bufHI[r][u * 4] = make_ushort4(f2bf(stg[i][0]), f2bf(stg[i][1]),
                                                   f2bf(stg[i][2]), f2bf(stg[i][3]));
    }
    __syncthreads();                                   // B3: h_j landed, bufHI ready

    // ---- R4: Q-GEMM + edge-MLP GEMM + stage h_j f32 -> regs ----
    f32x4 accQ[2][4] = {};
    proj_gemm(bufHI, wqT, accQ, lr, lq, w);
    f32x4 accE[2] = {};
    {
        const float* embrow = emb + ((size_t)g * TE + (lr & 3)) * DD;
        #pragma unroll
        for (int ks = 0; ks < 8; ++ks) {
            f32x4 e0 = *(const f32x4*)(embrow + ks * 32 + lq * 8);
            f32x4 e1 = *(const f32x4*)(embrow + ks * 32 + lq * 8 + 4);
            short8 ae;
            ae[0] = (short)f2bf(e0[0]); ae[1] = (short)f2bf(e0[1]);
            ae[2] = (short)f2bf(e0[2]); ae[3] = (short)f2bf(e0[3]);
            ae[4] = (short)f2bf(e1[0]); ae[5] = (short)f2bf(e1[1]);
            ae[6] = (short)f2bf(e1[2]); ae[7] = (short)f2bf(e1[3]);
            #pragma unroll
            for (int n = 0; n < 2; ++n) {
                const int col = w * 32 + n * 16 + lr;
                short8 bv = *(const short8*)(w1T + col * 256 + ks * 32 + lq * 8);
                accE[n] = __builtin_amdgcn_mfma_f32_16x16x32_bf16(ae, bv, accE[n], 0, 0, 0);
            }
        }
    }
    #pragma unroll
    for (int i = 0; i < 8; ++i) stg[i] = *(const f32x4*)(bufA32 + (i * 256 + t) * 4);
    __syncthreads();                                   // B4: all reads done

    // ---- R5: h_j bf16 -> bufHI ; Q+bias bf16 -> tQ (bufA reuse) ----
    #pragma unroll
    for (int i = 0; i < 8; ++i) {
        const int f = i * 256 + t, r = f >> 6, u = f & 63;
        *(ushort4*)&bufHI[r][u * 4] = make_ushort4(f2bf(stg[i][0]), f2bf(stg[i][1]),
                                                   f2bf(stg[i][2]), f2bf(stg[i][3]));
    }
    writeback(tQ, accQ, bq, lr, lq, w);
    __syncthreads();                                   // B5

    // ---- R6: K-GEMM ----
    f32x4 accK[2][4] = {};
    proj_gemm(bufHI, wkT, accK, lr, lq, w);
    __syncthreads();                                   // B6: bufHI/tK region free

    // ---- R7: K+bias bf16 -> tK ; edge-MLP epilogue -> sEdgeP ----
    writeback(tK, accK, bk, lr, lq, w);
    {
        float p[4] = {0.f, 0.f, 0.f, 0.f};
        #pragma unroll
        for (int n = 0; n < 2; ++n) {
            const int col = w * 32 + n * 16 + lr;
            const float b1 = be1[col], w2 = We2[col];
            #pragma unroll
            for (int v = 0; v < 4; ++v)                 // row lq*4+v ≡ edge v (dup rows)
                p[v] += gelu_exact(accE[n][v] + b1) * w2;
        }
        #pragma unroll
        for (int off = 1; off < 16; off <<= 1) {
            #pragma unroll
            for (int v = 0; v < 4; ++v) p[v] += __shfl_xor(p[v], off);
        }
        if (l == 0) {
            sEdgeP[w][0] = p[0]; sEdgeP[w][1] = p[1];
            sEdgeP[w][2] = p[2]; sEdgeP[w][3] = p[3];
        }
    }
    __syncthreads();                                   // B7: tiles + sEdgeP ready

    // ---- R8: scores via MFMA, softmax over k, diagonal mean ----
    float contrib = 0.f;
    #pragma unroll
    for (int h = 0; h < 4; ++h) {
        f32x4 s = {};
        #pragma unroll
        for (int ks = 0; ks < 2; ++ks) {
            short8 qa = *(const short8*)&tQ[w * 8 + (lr & 7)][h * 64 + ks * 32 + lq * 8];
            short8 kb = *(const short8*)&tK[w * 8 + (lr & 7)][h * 64 + ks * 32 + lq * 8];
            s = __builtin_amdgcn_mfma_f32_16x16x32_bf16(qa, kb, s, 0, 0, 0);
        }
        // lane holds S[q=lq*4+v][k=lr] (rows/cols >=8 are duplicates)
        #pragma unroll
        for (int v = 0; v < 4; ++v) {
            float sc = s[v] * SCALE_V;
            float m = sc;
            m = fmaxf(m, __shfl_xor(m, 1));
            m = fmaxf(m, __shfl_xor(m, 2));
            m = fmaxf(m, __shfl_xor(m, 4));            // max over k=0..7 (stays in lr&7 group)
            float pe = __expf(sc - m);
            float sum = pe;
            sum += __shfl_xor(sum, 1);
            sum += __shfl_xor(sum, 2);
            sum += __shfl_xor(sum, 4);
            if (lq < 2 && lr == lq * 4 + v) contrib += pe / sum;   // diag, q<8 only
        }
    }
    #pragma unroll
    for (int off = 1; off < 64; off <<= 1) contrib += __shfl_xor(contrib, off);
    const float act = contrib * (1.0f / 32.0f);        // mean over NH*K = 32

    // ---- R9: final 3 -> 16 -> 1 MLP (lanes 0..15 of each wave) ----
    const float es = sigmoidf(sEdgeP[0][w] + sEdgeP[1][w] + sEdgeP[2][w] +
                              sEdgeP[3][w] + be2[0]);
    float r = 0.f;
    if (l < 16) {
        float z = attr * Wo1[l] + act * Wo1[16 + l] + es * Wo1[32 + l] + bo1[l];
        r = gelu_exact(z) * Wo2[l];
    }
    r += __shfl_xor(r, 1);
    r += __shfl_xor(r, 2);
    r += __shfl_xor(r, 4);
    r += __shfl_xor(r, 8);
    if (l == 0) out[e] = sigmoidf(r + bo2[0]);
}

// ---------------------------------------------------------------------------
extern "C" void kernel_launch(void* const* d_in, const int* in_sizes, int n_in,
                              void* d_out, int out_size, void* d_ws, size_t ws_size,
                              hipStream_t stream) {
    const float* x_i  = (const float*)d_in[0];
    const float* x_j  = (const float*)d_in[1];
    const float* h_i  = (const float*)d_in[2];
    const float* h_j  = (const float*)d_in[3];
    const float* emb  = (const float*)d_in[4];
    const float* Wq   = (const float*)d_in[5];
    const float* bq   = (const float*)d_in[6];
    const float* Wk   = (const float*)d_in[7];
    const float* bk   = (const float*)d_in[8];
    const float* We1  = (const float*)d_in[9];
    const float* be1  = (const float*)d_in[10];
    const float* We2  = (const float*)d_in[11];
    const float* be2  = (const float*)d_in[12];
    const float* Wo1  = (const float*)d_in[13];
    const float* bo1  = (const float*)d_in[14];
    const float* Wo2  = (const float*)d_in[15];
    const float* bo2  = (const float*)d_in[16];
    float* out = (float*)d_out;

    // workspace: wqT 131072B | wkT 131072B | w1T 65536B
    unsigned short* wqT = (unsigned short*)d_ws;
    unsigned short* wkT = wqT + 65536;
    unsigned short* w1T = wkT + 65536;

    prep_weights<<<640, 256, 0, stream>>>(Wq, Wk, We1, wqT, wkT, w1T);
    fused_all<<<NGROUP, 256, 0, stream>>>(x_i, x_j, h_i, h_j, emb,
                                          wqT, wkT, w1T,
                                          bq, bk, be1, We2, be2,
                                          Wo1, bo1, Wo2, bo2, out);
}